// Round 12
// baseline (239.030 us; speedup 1.0000x reference)
//
#include <hip/hip_runtime.h>

// FFB encoder fused kernel, MI355X (gfx950). Round 12.
//  vs round 11: attack the LDS pipe (modeled ~77us, largest single pipe).
//   1) GEMM1 computes C^T by SWAPPING MFMA operands: MFMA(wh_frag, x_frag).
//      A/B frag layouts are index-identical (lane&31 -> M/N, (lane>>5)*8+j
//      -> K), so packed weights and x ds_reads are unchanged. C/D layout now
//      puts runs of 4 CONSECUTIVE COLUMNS (same row) in each lane's regs ->
//      epilogue x-writes become 16 ds_write_b64 instead of 64 ds_write_b16.
//      Grid-branch MFMAs swap args the same way (G^T). Bias is now
//      reg-indexed: folded into C1 init via 32 L1-hit global loads.
//   2) Head GEMM -> 32x32x16, ONE tile per wave (rows (w&1)*32, cols
//      (w>>1)*32): x ds_reads halve (32 -> 16 b128), stores stay coalesced,
//      bias stays lane-uniform. whh repacked for 32x32 (same size).
//   LDS cyc/wave-layer ~1150 -> ~730. Registers ~130 peak -> keep (256,3).
//  Kept: TM=64, f16 single-product, gf hi-only (2^(l-1) prescale), LDS
//  40960 B = 4 blocks/CU, 3-deep wh ring, 2 barriers/layer.

#define TM 64
#define XSTRIDE 264
#define GSTRIDE 48
#define K5 0.79577471545947667f         // 5/(2*pi)

typedef __attribute__((ext_vector_type(8))) _Float16 v8h;
typedef __attribute__((ext_vector_type(2))) unsigned int v2u;
typedef __attribute__((ext_vector_type(16))) float v16f;

#define MFMA32H(a, b, c) __builtin_amdgcn_mfma_f32_32x32x16_f16(a, b, c, 0, 0, 0)

__device__ __forceinline__ float sin_rev(float u) {
#if __has_builtin(__builtin_amdgcn_fractf)
    return __builtin_amdgcn_sinf(__builtin_amdgcn_fractf(u));
#else
    return __builtin_amdgcn_sinf(u - floorf(u));
#endif
}

__device__ __forceinline__ unsigned int f16u(float x) {   // RNE f32->f16 bits
    _Float16 hh = (_Float16)x;
    return (unsigned int)(unsigned short)__builtin_bit_cast(short, hh);
}
__device__ __forceinline__ short f16s(float x) {
    _Float16 hh = (_Float16)x;
    return __builtin_bit_cast(short, hh);
}

// ---------------- weight packing ----------------
// wh  f16: [l][kb16][nt8][lane64][8]  (327680 shorts), scaled by K5 (as R9)
// whh f16: [l][kb16][ct2][lane64][8]  (81920 shorts),  scaled by K5, 32x32
// gf  f16: [l][nt8][lane64][8]        (20480 shorts),  ffnA*2^(l-1)
__global__ __launch_bounds__(256) void ffb_pack(
    const float* __restrict__ Wh, const float* __restrict__ Whh,
    const float* __restrict__ ffnA,
    short* __restrict__ wh, short* __restrict__ whh, short* __restrict__ gf)
{
    int t = blockIdx.x * 256 + threadIdx.x;
    if (t < 40960) {                       // (l, kb, nt, lane)
        int lane = t & 63, nt = (t >> 6) & 7, kb = (t >> 9) & 15, l = t >> 13;
        int n = nt * 32 + (lane & 31);
        int k0 = kb * 16 + (lane >> 5) * 8;
        short hs[8];
        #pragma unroll
        for (int jj = 0; jj < 8; jj++)
            hs[jj] = f16s(Wh[(l * 256 + k0 + jj) * 256 + n] * K5);
        *(v8h*)(wh + t * 8) = *(v8h*)hs;
    } else if (t < 51200) {
        int t2 = t - 40960;                // (l, kb, ct, lane) - 32x32 frags
        int lane = t2 & 63, ct = (t2 >> 6) & 1, kb = (t2 >> 7) & 15, l = t2 >> 11;
        int n = ct * 32 + (lane & 31);
        int k0 = kb * 16 + (lane >> 5) * 8;
        short hs[8];
        #pragma unroll
        for (int jj = 0; jj < 8; jj++)
            hs[jj] = f16s(Whh[(l * 256 + k0 + jj) * 64 + n] * K5);
        *(v8h*)(whh + t2 * 8) = *(v8h*)hs;
    } else if (t < 53760) {
        int t3 = t - 51200;                // (l, nt, lane)
        int lane = t3 & 63, nt = (t3 >> 6) & 7, l = t3 >> 9;
        int n = nt * 32 + (lane & 31);
        const float sc = 0.5f * (float)(1 << l);       // 2^(l-1), exact
        short hs[8];
        #pragma unroll
        for (int jj = 0; jj < 8; jj++)
            hs[jj] = f16s(ffnA[(l * 8 + jj) * 256 + n] * sc);
        *(v8h*)(gf + t3 * 8) = *(v8h*)hs;
    }
}

// ---------------- main fused kernel ----------------
__global__ __launch_bounds__(256, 3) void ffb_main(
    const float* __restrict__ pos, const float* __restrict__ gfeat,
    const float* __restrict__ W0, const float* __restrict__ b0,
    const float* __restrict__ bh, const float* __restrict__ bhh,
    const short* __restrict__ wh, const short* __restrict__ whh,
    const short* __restrict__ gf,
    float* __restrict__ out)
{
    __shared__ __align__(16) short s_x[TM * XSTRIDE];   // f16  (33792 B)
    __shared__ __align__(16) short s_g[TM * GSTRIDE];   // f16  (6144 B)
    __shared__ float s_pos[TM * 3];                     //      (768 B)

    const int tid = threadIdx.x;
    const int row0 = blockIdx.x * TM;
    const int lane = tid & 63;
    const int w = tid >> 6;
    const int m32 = lane & 31;
    const int h = lane >> 5;

    if (tid < TM * 3) s_pos[tid] = pos[row0 * 3 + tid];
    for (int k2 = tid; k2 < TM * 40; k2 += 256) {
        int r = k2 / 40, f = k2 % 40;
        s_g[r * GSTRIDE + f] = f16s(gfeat[row0 * 40 + k2]);
    }
    __syncthreads();

    // layer 0: x = sin(5*(pos@W0 + b0))
    {
        const int c = tid;
        const float w00 = W0[c], w01 = W0[256 + c], w02 = W0[512 + c], bc = b0[c];
        #pragma unroll 4
        for (int r = 0; r < TM; r++) {
            float d = s_pos[r * 3 + 0] * w00 + s_pos[r * 3 + 1] * w01
                    + s_pos[r * 3 + 2] * w02 + bc;
            s_x[r * XSTRIDE + c] = f16s(sin_rev(d * K5));
        }
    }
    __syncthreads();

    float cout[16];
    #pragma unroll
    for (int r = 0; r < 16; r++) cout[r] = 0.f;

    // x B-frag offsets (GEMM1: n-tiles = row-tiles)
    const int a1off0 = m32 * XSTRIDE + h * 8;            // rows 0-31, + kb*16
    const int a1off1 = (32 + m32) * XSTRIDE + h * 8;     // rows 32-63
    // head: A-frag rows (w&1)*32, cols (w>>1)*32
    const int arowt = ((w & 1) * 32 + m32) * XSTRIDE + h * 8;
    const int hct = w >> 1;

    for (int l = 0; l < 5; l++) {
        // ---- C1 init with reg-indexed bias (C^T layout: cols in regs) ----
        v16f C1[2][2];                    // [nt(row-tile)][mt(col-tile)]
        #pragma unroll
        for (int mt = 0; mt < 2; mt++) {
            const float* bb = bh + l * 256 + w * 64 + mt * 32 + 4 * h;
            #pragma unroll
            for (int r = 0; r < 16; r++) {
                float bv = bb[(r & 3) + 8 * (r >> 2)] * K5;
                C1[0][mt][r] = bv; C1[1][mt][r] = bv;
            }
        }
        v8h gb0 = *(const v8h*)(gf + ((l * 8 + w * 2 + 0) * 64 + lane) * 8);
        v8h gb1 = *(const v8h*)(gf + ((l * 8 + w * 2 + 1) * 64 + lane) * 8);

        // ---- GEMM1 (swapped): C^T[col][row], A=wh frags, B=x frags ----
        {
            const short* bp = wh + l * 65536 + (2 * w) * 512 + lane * 8;
            v8h rb0[4], rb1[4];
            #pragma unroll
            for (int p = 0; p < 3; p++) {
                rb0[p] = *(const v8h*)(bp + p * 4096);
                rb1[p] = *(const v8h*)(bp + p * 4096 + 512);
            }
            #pragma unroll
            for (int kb = 0; kb < 16; kb++) {
                if (kb + 3 < 16) {
                    rb0[(kb + 3) & 3] = *(const v8h*)(bp + (kb + 3) * 4096);
                    rb1[(kb + 3) & 3] = *(const v8h*)(bp + (kb + 3) * 4096 + 512);
                }
                v8h x0 = *(const v8h*)&s_x[a1off0 + kb * 16];
                v8h x1 = *(const v8h*)&s_x[a1off1 + kb * 16];
                v8h bc0 = rb0[kb & 3], bc1 = rb1[kb & 3];
                C1[0][0] = MFMA32H(bc0, x0, C1[0][0]);
                C1[0][1] = MFMA32H(bc1, x0, C1[0][1]);
                C1[1][0] = MFMA32H(bc0, x1, C1[1][0]);
                C1[1][1] = MFMA32H(bc1, x1, C1[1][1]);
            }
        }
        __syncthreads();   // all waves done reading x_l

        // ---- epilogue: x = sin(C1) + sin(G); lane = one row, regs = cols
        //      in runs of 4 -> ds_write_b64 per run ----
        #pragma unroll
        for (int nt = 0; nt < 2; nt++) {
            v8h ga = *(const v8h*)&s_g[(nt * 32 + m32) * GSTRIDE + l * 8];
            const int rowi = (nt * 32 + m32) * XSTRIDE;
            #pragma unroll
            for (int mt = 0; mt < 2; mt++) {
                v16f Z = {};
                v16f G = MFMA32H((mt ? gb1 : gb0), ga, Z);   // G^T, same layout
                const int colb = w * 64 + mt * 32 + 4 * h;
                #pragma unroll
                for (int rr = 0; rr < 4; rr++) {
                    float v0 = sin_rev(C1[nt][mt][rr * 4 + 0]) + sin_rev(G[rr * 4 + 0]);
                    float v1 = sin_rev(C1[nt][mt][rr * 4 + 1]) + sin_rev(G[rr * 4 + 1]);
                    float v2 = sin_rev(C1[nt][mt][rr * 4 + 2]) + sin_rev(G[rr * 4 + 2]);
                    float v3 = sin_rev(C1[nt][mt][rr * 4 + 3]) + sin_rev(G[rr * 4 + 3]);
                    unsigned int u01 = f16u(v0) | (f16u(v1) << 16);
                    unsigned int u23 = f16u(v2) | (f16u(v3) << 16);
                    *(v2u*)&s_x[rowi + colb + 8 * rr] = (v2u){u01, u23};
                }
            }
        }
        __syncthreads();   // new x visible

        // ---- GEMM2: head, 32x32x16, ONE tile/wave (unswapped) ----
        const float b2 = bhh[l * 64 + hct * 32 + m32] * K5;
        v16f C2;
        #pragma unroll
        for (int r = 0; r < 16; r++) C2[r] = b2;
        {
            const short* bp = whh + l * 16384 + hct * 512 + lane * 8;
            v8h rb[4];
            #pragma unroll
            for (int p = 0; p < 3; p++)
                rb[p] = *(const v8h*)(bp + p * 1024);
            #pragma unroll
            for (int kb = 0; kb < 16; kb++) {
                if (kb + 3 < 16)
                    rb[(kb + 3) & 3] = *(const v8h*)(bp + (kb + 3) * 1024);
                v8h a = *(const v8h*)&s_x[arowt + kb * 16];
                C2 = MFMA32H(a, rb[kb & 3], C2);
            }
        }
        #pragma unroll
        for (int r = 0; r < 16; r++)
            cout[r] += sin_rev(C2[r]);
        // no barrier: next GEMM1 reads same x; overwrites after its own barrier
    }

    // ---- store x_out (C-layout: col=lane, rows in regs -> coalesced) ----
    #pragma unroll
    for (int r = 0; r < 16; r++) {
        const int row = (w & 1) * 32 + (r & 3) + 8 * (r >> 2) + 4 * h;
        out[(row0 + row) * 64 + hct * 32 + m32] = cout[r];
    }
}

extern "C" void kernel_launch(void* const* d_in, const int* in_sizes, int n_in,
                              void* d_out, int out_size, void* d_ws, size_t ws_size,
                              hipStream_t stream) {
    const float* pos   = (const float*)d_in[0];
    const float* gfeat = (const float*)d_in[1];
    const float* ffnA  = (const float*)d_in[2];
    const float* W0    = (const float*)d_in[3];
    const float* b0    = (const float*)d_in[4];
    const float* Wh    = (const float*)d_in[5];
    const float* bh    = (const float*)d_in[6];
    const float* Whh   = (const float*)d_in[7];
    const float* bhh   = (const float*)d_in[8];
    float* out = (float*)d_out;
    const int N = in_sizes[0] / 3;

    // ws (shorts): wh 327680 | whh 81920 | gf 20480   (0.86 MB)
    short* wh  = (short*)d_ws;
    short* whh = wh + 327680;
    short* gf  = whh + 81920;

    ffb_pack<<<210, 256, 0, stream>>>(Wh, Whh, ffnA, wh, whh, gf);
    ffb_main<<<N / TM, 256, 0, stream>>>(pos, gfeat, W0, b0, bh, bhh,
                                         wh, whh, gf, out);
}